// Round 9
// baseline (107.093 us; speedup 1.0000x reference)
//
#include <hip/hip_runtime.h>
#include <hip/hip_bf16.h>

// Problem dims (fixed by reference): B=64 S=256 F=4 V=50257 H=768 D=512
#define M_TOT 16384   // B*S
#define K_TOT 768     // H
#define N_TOT 512     // D
#define NT 12         // K_TOT / 64 K-chunks
#define NSLOT 96      // 16B-slots per A row (768*2B / 16B)

typedef __attribute__((ext_vector_type(8))) __bf16 bf16x8;
typedef __attribute__((ext_vector_type(4))) float f32x4;

static __device__ __forceinline__ ushort f2bf(float x) {
  union { float f; unsigned int u; } v; v.f = x;
  unsigned int r = v.u + 0x7fffu + ((v.u >> 16) & 1u);
  return (ushort)(r >> 16);
}
static __device__ __forceinline__ unsigned pack2(float lo, float hi) {
  return (unsigned)f2bf(lo) | ((unsigned)f2bf(hi) << 16);
}

// ---------------------------------------------------------------------------
// Kernel 1: W[768][512] f32 -> Wt_frag bf16 fragment-major:
//   W[k][col] -> Wt[ ((k>>3)*512 + col)*8 + (k&7) ]
// ---------------------------------------------------------------------------
__global__ __launch_bounds__(256) void wt_kernel(const float* __restrict__ W,
                                                 ushort* __restrict__ Wt) {
  __shared__ float tile[64][65];
  const int t  = threadIdx.x;
  const int k0 = blockIdx.x * 64;
  const int n0 = blockIdx.y * 64;
#pragma unroll
  for (int i = 0; i < 4; ++i) {
    const int idx = t + i * 256;
    const int r = idx >> 4;
    const int c = (idx & 15) * 4;
    const float4 v =
        *reinterpret_cast<const float4*>(W + (size_t)(k0 + r) * N_TOT + n0 + c);
    tile[r][c + 0] = v.x; tile[r][c + 1] = v.y;
    tile[r][c + 2] = v.z; tile[r][c + 3] = v.w;
  }
  __syncthreads();
#pragma unroll
  for (int i = 0; i < 4; ++i) {
    const int idx = t + i * 256;
    const int rn = idx >> 4;        // col within tile
    const int ck = (idx & 15) * 4;  // k within tile
    ushort4 o;
    o.x = f2bf(tile[ck + 0][rn]);
    o.y = f2bf(tile[ck + 1][rn]);
    o.z = f2bf(tile[ck + 2][rn]);
    o.w = f2bf(tile[ck + 3][rn]);
    const int kg    = k0 + ck;
    const int chunk = kg >> 3;
    const int e0    = kg & 7;
    *reinterpret_cast<ushort4*>(
        &Wt[((size_t)chunk * N_TOT + n0 + rn) * 8 + e0]) = o;
  }
}

// ---------------------------------------------------------------------------
// Kernel 2 (FUSED, producer/consumer): out = mean-gather(E,words) @ W + bias.
// 256 blocks (1/CU) x 512 threads. Waves 0-3 = PRODUCERS: gather E rows ->
// A-LDS (mask-FMA + bf16 pack), never MFMA. Waves 4-7 = CONSUMERS: MFMA with
// B-fragments direct from L2-resident fragment-major Wt, never touch E.
// Rationale: vmcnt is a per-wave IN-ORDER counter, so mixing HBM E-loads and
// L2 B-loads in one wave serializes MFMA behind HBM latency (R8 lesson).
// Split waves -> consumer vmcnt counts only ~200cyc L2 loads.
// Pipeline per block (64 rows = 2 sub-tiles of 32, A0/A1 buffers):
//   P: gather S0 | bar1 | gather S1          | bar2 |
//   C:           | bar1 | GEMM(S0)+store(S0) | bar2 | GEMM(S1)+store(S1)
// ---------------------------------------------------------------------------
__global__ __launch_bounds__(512, 1) void fused_kernel(
    const int* __restrict__ words, const float* __restrict__ E,
    const ushort* __restrict__ Wt, const float* __restrict__ bias,
    float* __restrict__ out) {
  __shared__ ushort A0[32 * NSLOT * 8];  // 48 KB
  __shared__ ushort A1[32 * NSLOT * 8];  // 48 KB
  __shared__ int   eoff_l[64][4];
  __shared__ float msk_l[64][4];
  __shared__ float scl_l[64];

  const int t  = threadIdx.x;
  const int w  = t >> 6;   // wave 0..7
  const int bm = blockIdx.x;

  // ---- metadata for all 64 rows ----
  if (t < 64) {
    const int4 w4 =
        *reinterpret_cast<const int4*>(words + (size_t)(bm * 64 + t) * 4);
    const int ids[4] = {w4.x, w4.y, w4.z, w4.w};
    float cnt = 0.f;
#pragma unroll
    for (int f = 0; f < 4; ++f) {
      eoff_l[t][f] = ids[f] * K_TOT;
      const float m = (ids[f] != 0) ? 1.f : 0.f;
      msk_l[t][f] = m;
      cnt += m;
    }
    scl_l[t] = (cnt > 0.f) ? (1.f / cnt) : 0.f;
  }
  __syncthreads();

  if (w < 4) {
    // =============== PRODUCER: 256 threads gather 32 rows/sub-tile ========
    const int sr  = t >> 3;        // 0..31 row within sub-tile
    const int seg = t & 7;         // 16B-pair segment (32B per kt per thread)
    const int sw  = seg ^ (sr & 7);

    // [S][f]: S=0 -> row sr, S=1 -> row 32+sr. Indexed by literals only.
    const float4* pf[2][4];
#pragma unroll
    for (int f = 0; f < 4; ++f) {
      pf[0][f] = reinterpret_cast<const float4*>(E + eoff_l[sr][f] + seg * 8);
      pf[1][f] =
          reinterpret_cast<const float4*>(E + eoff_l[32 + sr][f] + seg * 8);
    }
    const float mk[2][4] = {
        {msk_l[sr][0], msk_l[sr][1], msk_l[sr][2], msk_l[sr][3]},
        {msk_l[32 + sr][0], msk_l[32 + sr][1], msk_l[32 + sr][2],
         msk_l[32 + sr][3]}};
    const float sc[2] = {scl_l[sr], scl_l[32 + sr]};

    float4 vgA[8], vgB[8];  // two in-flight groups (static names, rule #20)

#define P_LOAD(vg, S, kt)                                                    \
  do {                                                                       \
    _Pragma("unroll") for (int f = 0; f < 4; ++f) {                          \
      vg[2 * f + 0] = pf[S][f][(kt) * 16 + 0];                               \
      vg[2 * f + 1] = pf[S][f][(kt) * 16 + 1];                               \
    }                                                                        \
  } while (0)

#define P_MATH(vg, dst, S, kt)                                               \
  do {                                                                       \
    float s[8];                                                              \
    _Pragma("unroll") for (int j = 0; j < 4; ++j) {                          \
      s[j] = (vg[0][j] * mk[S][0] + vg[2][j] * mk[S][1] +                    \
              vg[4][j] * mk[S][2] + vg[6][j] * mk[S][3]) * sc[S];            \
      s[4 + j] = (vg[1][j] * mk[S][0] + vg[3][j] * mk[S][1] +                \
                  vg[5][j] * mk[S][2] + vg[7][j] * mk[S][3]) * sc[S];        \
    }                                                                        \
    uint4 o;                                                                 \
    o.x = pack2(s[0], s[1]); o.y = pack2(s[2], s[3]);                        \
    o.z = pack2(s[4], s[5]); o.w = pack2(s[6], s[7]);                        \
    *reinterpret_cast<uint4*>(&(dst)[(sr * NSLOT + (kt) * 8 + sw) * 8]) = o; \
  } while (0)

    // ---- gather S0 -> A0 (depth-2 pipeline; row read contiguously) ----
    P_LOAD(vgA, 0, 0);      P_LOAD(vgB, 0, 1);
    P_MATH(vgA, A0, 0, 0);  P_LOAD(vgA, 0, 2);
    P_MATH(vgB, A0, 0, 1);  P_LOAD(vgB, 0, 3);
    P_MATH(vgA, A0, 0, 2);  P_LOAD(vgA, 0, 4);
    P_MATH(vgB, A0, 0, 3);  P_LOAD(vgB, 0, 5);
    P_MATH(vgA, A0, 0, 4);  P_LOAD(vgA, 0, 6);
    P_MATH(vgB, A0, 0, 5);  P_LOAD(vgB, 0, 7);
    P_MATH(vgA, A0, 0, 6);  P_LOAD(vgA, 0, 8);
    P_MATH(vgB, A0, 0, 7);  P_LOAD(vgB, 0, 9);
    P_MATH(vgA, A0, 0, 8);  P_LOAD(vgA, 0, 10);
    P_MATH(vgB, A0, 0, 9);  P_LOAD(vgB, 0, 11);
    P_MATH(vgA, A0, 0, 10);
    P_MATH(vgB, A0, 0, 11);
    __syncthreads();  // bar1: A0 ready

    // ---- gather S1 -> A1 (concurrent with consumers' GEMM(S0)) ----
    P_LOAD(vgA, 1, 0);      P_LOAD(vgB, 1, 1);
    P_MATH(vgA, A1, 1, 0);  P_LOAD(vgA, 1, 2);
    P_MATH(vgB, A1, 1, 1);  P_LOAD(vgB, 1, 3);
    P_MATH(vgA, A1, 1, 2);  P_LOAD(vgA, 1, 4);
    P_MATH(vgB, A1, 1, 3);  P_LOAD(vgB, 1, 5);
    P_MATH(vgA, A1, 1, 4);  P_LOAD(vgA, 1, 6);
    P_MATH(vgB, A1, 1, 5);  P_LOAD(vgB, 1, 7);
    P_MATH(vgA, A1, 1, 6);  P_LOAD(vgA, 1, 8);
    P_MATH(vgB, A1, 1, 7);  P_LOAD(vgB, 1, 9);
    P_MATH(vgA, A1, 1, 8);  P_LOAD(vgA, 1, 10);
    P_MATH(vgB, A1, 1, 9);  P_LOAD(vgB, 1, 11);
    P_MATH(vgA, A1, 1, 10);
    P_MATH(vgB, A1, 1, 11);
    __syncthreads();  // bar2: A1 ready
#undef P_LOAD
#undef P_MATH
  } else {
    // =============== CONSUMER: 4 waves x 128-col slabs ====================
    const int lane = t & 63;
    const int cw   = w - 4;          // 0..3
    const int rsel = lane & 15;
    const int ksel = lane >> 4;
    const int colBase = cw * 128 + rsel;

    f32x4 acc[2][8];

#define C_COMPUTE(Asrc, kt)                                                  \
  do {                                                                       \
    _Pragma("unroll") for (int kk = 0; kk < 2; ++kk) {                       \
      const int ks = kk * 4 + ksel;                                          \
      bf16x8 af[2], bfr[8];                                                  \
      _Pragma("unroll") for (int m = 0; m < 2; ++m) {                        \
        const int r = m * 16 + rsel;                                         \
        af[m] = *reinterpret_cast<const bf16x8*>(                            \
            &(Asrc)[(r * NSLOT + (kt) * 8 + (ks ^ (r & 7))) * 8]);           \
      }                                                                      \
      _Pragma("unroll") for (int n = 0; n < 8; ++n)                          \
        bfr[n] = *reinterpret_cast<const bf16x8*>(                           \
            &Wt[((size_t)((kt) * 8 + ks) * N_TOT + colBase + n * 16) * 8]);  \
      __builtin_amdgcn_s_setprio(1);                                         \
      _Pragma("unroll") for (int m = 0; m < 2; ++m)                          \
        _Pragma("unroll") for (int n = 0; n < 8; ++n)                        \
          acc[m][n] = __builtin_amdgcn_mfma_f32_16x16x32_bf16(               \
              af[m], bfr[n], acc[m][n], 0, 0, 0);                            \
      __builtin_amdgcn_s_setprio(0);                                         \
    }                                                                        \
  } while (0)

#define C_EPILOGUE(T)                                                        \
  do {                                                                       \
    const int row0 = bm * 64 + (T) * 32 + (ksel << 2);                       \
    _Pragma("unroll") for (int n = 0; n < 8; ++n) {                          \
      const float bv = bias[colBase + n * 16];                               \
      _Pragma("unroll") for (int m = 0; m < 2; ++m) {                        \
        _Pragma("unroll") for (int j = 0; j < 4; ++j) {                      \
          __builtin_nontemporal_store(                                       \
              acc[m][n][j] + bv,                                             \
              &out[(size_t)(row0 + m * 16 + j) * N_TOT + colBase + n * 16]); \
        }                                                                    \
      }                                                                      \
    }                                                                        \
  } while (0)

    __syncthreads();  // bar1: A0 ready
#pragma unroll
    for (int m = 0; m < 2; ++m)
#pragma unroll
      for (int n = 0; n < 8; ++n) acc[m][n] = (f32x4){0.f, 0.f, 0.f, 0.f};
#pragma unroll
    for (int kt = 0; kt < NT; ++kt) C_COMPUTE(A0, kt);
    C_EPILOGUE(0);
    __syncthreads();  // bar2: A1 ready
#pragma unroll
    for (int m = 0; m < 2; ++m)
#pragma unroll
      for (int n = 0; n < 8; ++n) acc[m][n] = (f32x4){0.f, 0.f, 0.f, 0.f};
#pragma unroll
    for (int kt = 0; kt < NT; ++kt) C_COMPUTE(A1, kt);
    C_EPILOGUE(1);
#undef C_COMPUTE
#undef C_EPILOGUE
  }
}

// ---------------------------------------------------------------------------
extern "C" void kernel_launch(void* const* d_in, const int* in_sizes, int n_in,
                              void* d_out, int out_size, void* d_ws,
                              size_t ws_size, hipStream_t stream) {
  const int*   words = (const int*)d_in[0];
  const float* E     = (const float*)d_in[1];
  const float* W     = (const float*)d_in[2];
  const float* b     = (const float*)d_in[3];
  float* out = (float*)d_out;

  ushort* Wtws = (ushort*)d_ws;  // 512*768 bf16, fragment-major

  hipLaunchKernelGGL(wt_kernel, dim3(K_TOT / 64, N_TOT / 64), dim3(256), 0,
                     stream, W, Wtws);
  hipLaunchKernelGGL(fused_kernel, dim3(M_TOT / 64), dim3(512), 0, stream,
                     words, E, Wtws, b, out);
}

// Round 10
// 64.408 us; speedup vs baseline: 1.6627x; 1.6627x over previous
//
#include <hip/hip_runtime.h>
#include <hip/hip_bf16.h>

// Problem dims (fixed by reference): B=64 S=256 F=4 V=50257 H=768 D=512
#define M_TOT 16384   // B*S
#define K_TOT 768     // H
#define N_TOT 512     // D
#define BM 16         // rows per block (small => ~25KB LDS => 6 blocks/CU)
#define NT 12         // K_TOT / 64 K-chunks
#define NSLOT 96      // 16B-slots per A row (768*2B / 16B)

typedef __attribute__((ext_vector_type(8))) __bf16 bf16x8;
typedef __attribute__((ext_vector_type(4))) float f32x4;

static __device__ __forceinline__ ushort f2bf(float x) {
  union { float f; unsigned int u; } v; v.f = x;
  unsigned int r = v.u + 0x7fffu + ((v.u >> 16) & 1u);
  return (ushort)(r >> 16);
}
static __device__ __forceinline__ unsigned pack2(float lo, float hi) {
  return (unsigned)f2bf(lo) | ((unsigned)f2bf(hi) << 16);
}

// ---------------------------------------------------------------------------
// Kernel 1: W[768][512] f32 -> Wt_frag bf16 fragment-major:
//   W[k][col] -> Wt[ ((k>>3)*512 + col)*8 + (k&7) ]
// ---------------------------------------------------------------------------
__global__ __launch_bounds__(256) void wt_kernel(const float* __restrict__ W,
                                                 ushort* __restrict__ Wt) {
  __shared__ float tile[64][65];
  const int t  = threadIdx.x;
  const int k0 = blockIdx.x * 64;
  const int n0 = blockIdx.y * 64;
#pragma unroll
  for (int i = 0; i < 4; ++i) {
    const int idx = t + i * 256;
    const int r = idx >> 4;
    const int c = (idx & 15) * 4;
    const float4 v =
        *reinterpret_cast<const float4*>(W + (size_t)(k0 + r) * N_TOT + n0 + c);
    tile[r][c + 0] = v.x; tile[r][c + 1] = v.y;
    tile[r][c + 2] = v.z; tile[r][c + 3] = v.w;
  }
  __syncthreads();
#pragma unroll
  for (int i = 0; i < 4; ++i) {
    const int idx = t + i * 256;
    const int rn = idx >> 4;        // col within tile
    const int ck = (idx & 15) * 4;  // k within tile
    ushort4 o;
    o.x = f2bf(tile[ck + 0][rn]);
    o.y = f2bf(tile[ck + 1][rn]);
    o.z = f2bf(tile[ck + 2][rn]);
    o.w = f2bf(tile[ck + 3][rn]);
    const int kg    = k0 + ck;
    const int chunk = kg >> 3;
    const int e0    = kg & 7;
    *reinterpret_cast<ushort4*>(
        &Wt[((size_t)chunk * N_TOT + n0 + rn) * 8 + e0]) = o;
  }
}

// ---------------------------------------------------------------------------
// Kernel 2 (FUSED, high-occupancy): out = mean-gather(E,words) @ W + bias.
// 1024 blocks (BM=16) x 256 threads (4 waves); ~25KB LDS -> 6 blocks/CU,
// ALL blocks co-resident (~16-24 waves/CU). Uniform waves (no role split —
// R9 counters showed role-split starved both pipes: HBM 14%, MFMA 4%).
// Per block: [gather 16 rows full-K -> A-LDS] barrier [GEMM 16x512].
// Phase overlap happens ACROSS the 6 resident blocks per CU, which desync
// naturally; each CU always has some blocks streaming HBM and some doing
// MFMA/L2. B-fragments read direct from fragment-major Wt (L2-resident,
// 768KB/XCD). A-LDS slot-swizzled (slot = seg ^ (row&7)) -> ~conflict-free.
// ---------------------------------------------------------------------------
__global__ __launch_bounds__(256) void fused_kernel(
    const int* __restrict__ words, const float* __restrict__ E,
    const ushort* __restrict__ Wt, const float* __restrict__ bias,
    float* __restrict__ out) {
  __shared__ ushort A_l[BM * NSLOT * 8];  // 24 KB
  __shared__ int   eoff_l[BM][4];
  __shared__ float msk_l[BM][4];
  __shared__ float scl_l[BM];

  const int t    = threadIdx.x;
  const int lane = t & 63;
  const int w    = t >> 6;   // 0..3: wave's 128-col slab
  const int bm   = blockIdx.x;

  // ---- per-row gather metadata (rows bm*16 .. +16) ----
  if (t < BM) {
    const int4 w4 =
        *reinterpret_cast<const int4*>(words + (size_t)(bm * BM + t) * 4);
    const int ids[4] = {w4.x, w4.y, w4.z, w4.w};
    float cnt = 0.f;
#pragma unroll
    for (int f = 0; f < 4; ++f) {
      eoff_l[t][f] = ids[f] * K_TOT;
      const float m = (ids[f] != 0) ? 1.f : 0.f;
      msk_l[t][f] = m;
      cnt += m;
    }
    scl_l[t] = (cnt > 0.f) ? (1.f / cnt) : 0.f;
  }
  __syncthreads();

  // ---- phase 1: gather. thread t covers row sr = t>>4; 16 threads/row
  // cover the 96 slots as s = (t&15) + 16*g, g=0..5 (slot = 8 k-elems). ----
  const int sr  = t >> 4;   // 0..15
  const int c16 = t & 15;   // 0..15
  const float4* pf[4];
#pragma unroll
  for (int f = 0; f < 4; ++f)
    pf[f] = reinterpret_cast<const float4*>(E + eoff_l[sr][f]);
  const float m0 = msk_l[sr][0], m1 = msk_l[sr][1];
  const float m2 = msk_l[sr][2], m3 = msk_l[sr][3];
  const float scl = scl_l[sr];

  float4 vgA[8], vgB[8];  // two in-flight groups (static names, rule #20)

#define G_LOAD(vg, g)                                                        \
  do {                                                                       \
    const int s_ = c16 + 16 * (g);                                           \
    _Pragma("unroll") for (int f = 0; f < 4; ++f) {                          \
      vg[2 * f + 0] = pf[f][s_ * 2 + 0];                                     \
      vg[2 * f + 1] = pf[f][s_ * 2 + 1];                                     \
    }                                                                        \
  } while (0)

#define G_MATH(vg, g)                                                        \
  do {                                                                       \
    const int s_  = c16 + 16 * (g);                                          \
    const int kt_ = s_ >> 3;                                                 \
    const int sw_ = (s_ & 7) ^ (sr & 7);                                     \
    float s[8];                                                              \
    _Pragma("unroll") for (int j = 0; j < 4; ++j) {                          \
      s[j] = (vg[0][j] * m0 + vg[2][j] * m1 + vg[4][j] * m2 + vg[6][j] * m3) \
             * scl;                                                          \
      s[4 + j] =                                                             \
          (vg[1][j] * m0 + vg[3][j] * m1 + vg[5][j] * m2 + vg[7][j] * m3) *  \
          scl;                                                               \
    }                                                                        \
    uint4 o;                                                                 \
    o.x = pack2(s[0], s[1]); o.y = pack2(s[2], s[3]);                        \
    o.z = pack2(s[4], s[5]); o.w = pack2(s[6], s[7]);                        \
    *reinterpret_cast<uint4*>(                                               \
        &A_l[(sr * NSLOT + kt_ * 8 + sw_) * 8]) = o;                         \
  } while (0)

  G_LOAD(vgA, 0);  G_LOAD(vgB, 1);
  G_MATH(vgA, 0);  G_LOAD(vgA, 2);
  G_MATH(vgB, 1);  G_LOAD(vgB, 3);
  G_MATH(vgA, 2);  G_LOAD(vgA, 4);
  G_MATH(vgB, 3);  G_LOAD(vgB, 5);
  G_MATH(vgA, 4);
  G_MATH(vgB, 5);
#undef G_LOAD
#undef G_MATH
  __syncthreads();  // A tile complete; only barrier in the kernel

  // ---- phase 2: GEMM. wave w: rows bm*16..+16 x cols [w*128, +128) ----
  f32x4 acc[8];
#pragma unroll
  for (int n = 0; n < 8; ++n) acc[n] = (f32x4){0.f, 0.f, 0.f, 0.f};

  const int rsel = lane & 15;   // A row / C col-within-16
  const int ksel = lane >> 4;   // 0..3
  const int colBase = w * 128 + rsel;

#pragma unroll
  for (int kt = 0; kt < NT; ++kt) {
#pragma unroll
    for (int kk = 0; kk < 2; ++kk) {
      const int ks = kk * 4 + ksel;  // 8-elem k-chunk within kt
      const bf16x8 af = *reinterpret_cast<const bf16x8*>(
          &A_l[(rsel * NSLOT + kt * 8 + (ks ^ (rsel & 7))) * 8]);
      bf16x8 bfr[8];
#pragma unroll
      for (int n = 0; n < 8; ++n)
        bfr[n] = *reinterpret_cast<const bf16x8*>(
            &Wt[((size_t)(kt * 8 + ks) * N_TOT + colBase + n * 16) * 8]);
      __builtin_amdgcn_s_setprio(1);
#pragma unroll
      for (int n = 0; n < 8; ++n)
        acc[n] = __builtin_amdgcn_mfma_f32_16x16x32_bf16(af, bfr[n], acc[n],
                                                         0, 0, 0);
      __builtin_amdgcn_s_setprio(0);
    }
  }

  // ---- epilogue: C col = lane&15 (+16n), row = (lane>>4)*4 + j ----
  const int row0 = bm * BM + (ksel << 2);
#pragma unroll
  for (int n = 0; n < 8; ++n) {
    const float bv = bias[colBase + n * 16];
#pragma unroll
    for (int j = 0; j < 4; ++j) {
      __builtin_nontemporal_store(
          acc[n][j] + bv,
          &out[(size_t)(row0 + j) * N_TOT + colBase + n * 16]);
    }
  }
}

// ---------------------------------------------------------------------------
extern "C" void kernel_launch(void* const* d_in, const int* in_sizes, int n_in,
                              void* d_out, int out_size, void* d_ws,
                              size_t ws_size, hipStream_t stream) {
  const int*   words = (const int*)d_in[0];
  const float* E     = (const float*)d_in[1];
  const float* W     = (const float*)d_in[2];
  const float* b     = (const float*)d_in[3];
  float* out = (float*)d_out;

  ushort* Wtws = (ushort*)d_ws;  // 512*768 bf16, fragment-major

  hipLaunchKernelGGL(wt_kernel, dim3(K_TOT / 64, N_TOT / 64), dim3(256), 0,
                     stream, W, Wtws);
  hipLaunchKernelGGL(fused_kernel, dim3(M_TOT / BM), dim3(256), 0, stream,
                     words, E, Wtws, b, out);
}

// Round 11
// 54.971 us; speedup vs baseline: 1.9482x; 1.1717x over previous
//
#include <hip/hip_runtime.h>
#include <hip/hip_bf16.h>

// Problem dims (fixed by reference): B=64 S=256 F=4 V=50257 H=768 D=512
#define M_TOT 16384   // B*S
#define K_TOT 768     // H
#define N_TOT 512     // D
#define BM 64         // rows per block; 256 blocks = 1/CU
#define NT 12         // K-chunks of 64

typedef __attribute__((ext_vector_type(8))) __bf16 bf16x8;
typedef __attribute__((ext_vector_type(4))) float f32x4;

static __device__ __forceinline__ ushort f2bf(float x) {
  union { float f; unsigned int u; } v; v.f = x;
  unsigned int r = v.u + 0x7fffu + ((v.u >> 16) & 1u);
  return (ushort)(r >> 16);
}
static __device__ __forceinline__ unsigned pack2(float lo, float hi) {
  return (unsigned)f2bf(lo) | ((unsigned)f2bf(hi) << 16);
}

// ---------------------------------------------------------------------------
// Kernel 1: W[768][512] f32 -> Wt_frag bf16 fragment-major:
//   W[k][col] -> Wt[ ((k>>3)*512 + col)*8 + (k&7) ]
// ---------------------------------------------------------------------------
__global__ __launch_bounds__(256) void wt_kernel(const float* __restrict__ W,
                                                 ushort* __restrict__ Wt) {
  __shared__ float tile[64][65];
  const int t  = threadIdx.x;
  const int k0 = blockIdx.x * 64;
  const int n0 = blockIdx.y * 64;
#pragma unroll
  for (int i = 0; i < 4; ++i) {
    const int idx = t + i * 256;
    const int r = idx >> 4;
    const int c = (idx & 15) * 4;
    const float4 v =
        *reinterpret_cast<const float4*>(W + (size_t)(k0 + r) * N_TOT + n0 + c);
    tile[r][c + 0] = v.x; tile[r][c + 1] = v.y;
    tile[r][c + 2] = v.z; tile[r][c + 3] = v.w;
  }
  __syncthreads();
#pragma unroll
  for (int i = 0; i < 4; ++i) {
    const int idx = t + i * 256;
    const int rn = idx >> 4;        // col within tile
    const int ck = (idx & 15) * 4;  // k within tile
    ushort4 o;
    o.x = f2bf(tile[ck + 0][rn]);
    o.y = f2bf(tile[ck + 1][rn]);
    o.z = f2bf(tile[ck + 2][rn]);
    o.w = f2bf(tile[ck + 3][rn]);
    const int kg    = k0 + ck;
    const int chunk = kg >> 3;
    const int e0    = kg & 7;
    *reinterpret_cast<ushort4*>(
        &Wt[((size_t)chunk * N_TOT + n0 + rn) * 8 + e0]) = o;
  }
}

// ---------------------------------------------------------------------------
// Kernel 2 (FUSED, phase-serial, contiguous-row gather):
//   out[16384][512] = mean-gather(E, words) @ W + bias
// 256 blocks (1/CU) x 512 threads (8 waves), BM=64, ~97KB LDS.
// Gather: wave owns 8 rows; per (row,id) the full 3KB E row is read as
// THREE back-to-back whole-wave dwordx4 loads (lane covers k = c*256+l*4+j)
// -> contiguous 1KB/instr, 3KB/row: max HBM row-buffer efficiency (the
// R6/R8 pattern read rows as 12 scattered 256B chunks). Depth-2 row
// pipeline; mask-FMA is lane-local (k resident in lane), same FMA order
// as prior rounds -> bit-identical output. LDS slot-swizzle ^= row&7.
// GEMM: B-fragments direct from L2-resident fragment-major Wt; acc 4x4;
// nontemporal out. One barrier total.
// ---------------------------------------------------------------------------
__global__ __launch_bounds__(512, 2) void fused_kernel(
    const int* __restrict__ words, const float* __restrict__ E,
    const ushort* __restrict__ Wt, const float* __restrict__ bias,
    float* __restrict__ out) {
  __shared__ ushort A_l[BM * 96 * 8];  // [row][slot 0..95][8 elems] = 96 KB
  __shared__ int   eoff_l[BM][4];
  __shared__ float msk_l[BM][4];
  __shared__ float scl_l[BM];

  const int t    = threadIdx.x;
  const int lane = t & 63;
  const int w    = t >> 6;   // 0..7
  const int bm   = blockIdx.x;

  // ---- per-row gather metadata (rows bm*64 .. +64) ----
  if (t < BM) {
    const int4 w4 =
        *reinterpret_cast<const int4*>(words + (size_t)(bm * BM + t) * 4);
    const int ids[4] = {w4.x, w4.y, w4.z, w4.w};
    float cnt = 0.f;
#pragma unroll
    for (int f = 0; f < 4; ++f) {
      eoff_l[t][f] = ids[f] * K_TOT;
      const float m = (ids[f] != 0) ? 1.f : 0.f;
      msk_l[t][f] = m;
      cnt += m;
    }
    scl_l[t] = (cnt > 0.f) ? (1.f / cnt) : 0.f;
  }
  __syncthreads();

  // ================= phase 1: gather (wave w owns rows w*8 .. +8) ==========
  const int rbase = w * 8;
  float4 vA[12], vB[12];  // two in-flight rows (static names, rule #20)

#define G_LOAD(vv, r)                                                        \
  do {                                                                       \
    const int row_ = rbase + (r);                                            \
    _Pragma("unroll") for (int f = 0; f < 4; ++f) {                          \
      const float4* p_ =                                                     \
          reinterpret_cast<const float4*>(E + eoff_l[row_][f]) + lane;       \
      vv[f * 3 + 0] = p_[0];                                                 \
      vv[f * 3 + 1] = p_[64];                                                \
      vv[f * 3 + 2] = p_[128];                                               \
    }                                                                        \
  } while (0)

#define G_MATH(vv, r)                                                        \
  do {                                                                       \
    const int row_ = rbase + (r);                                            \
    const float km0 = msk_l[row_][0], km1 = msk_l[row_][1];                  \
    const float km2 = msk_l[row_][2], km3 = msk_l[row_][3];                  \
    const float ksc = scl_l[row_];                                           \
    _Pragma("unroll") for (int c = 0; c < 3; ++c) {                          \
      float s[4];                                                            \
      _Pragma("unroll") for (int j = 0; j < 4; ++j)                          \
        s[j] = (vv[0 * 3 + c][j] * km0 + vv[1 * 3 + c][j] * km1 +            \
                vv[2 * 3 + c][j] * km2 + vv[3 * 3 + c][j] * km3) * ksc;      \
      uint2 o_;                                                              \
      o_.x = pack2(s[0], s[1]);                                              \
      o_.y = pack2(s[2], s[3]);                                              \
      const int slot_ = c * 32 + ((lane >> 1) ^ (r));  /* swizzle ^ row&7 */ \
      *reinterpret_cast<uint2*>(                                             \
          &A_l[row_ * 768 + slot_ * 8 + (lane & 1) * 4]) = o_;               \
    }                                                                        \
  } while (0)

  G_LOAD(vA, 0);  G_LOAD(vB, 1);
  G_MATH(vA, 0);  G_LOAD(vA, 2);
  G_MATH(vB, 1);  G_LOAD(vB, 3);
  G_MATH(vA, 2);  G_LOAD(vA, 4);
  G_MATH(vB, 3);  G_LOAD(vB, 5);
  G_MATH(vA, 4);  G_LOAD(vA, 6);
  G_MATH(vB, 5);  G_LOAD(vB, 7);
  G_MATH(vA, 6);
  G_MATH(vB, 7);
#undef G_LOAD
#undef G_MATH
  __syncthreads();  // A tile complete; only barrier in the kernel

  // ================= phase 2: GEMM (wave w: 64 rows x cols [w*64,+64)) =====
  f32x4 acc[4][4];
#pragma unroll
  for (int m = 0; m < 4; ++m)
#pragma unroll
    for (int n = 0; n < 4; ++n) acc[m][n] = (f32x4){0.f, 0.f, 0.f, 0.f};

  const int rsel = lane & 15;   // A row-within-16 / C col-within-16
  const int ksel = lane >> 4;   // 0..3
  const int colBase = w * 64 + rsel;

#pragma unroll
  for (int kt = 0; kt < NT; ++kt) {
#pragma unroll
    for (int kk = 0; kk < 2; ++kk) {
      const int g = kt * 8 + kk * 4 + ksel;  // global 8-elem k-chunk 0..95
      bf16x8 af[4], bfr[4];
#pragma unroll
      for (int m = 0; m < 4; ++m) {
        const int r_ = m * 16 + rsel;
        af[m] = *reinterpret_cast<const bf16x8*>(
            &A_l[r_ * 768 + (g ^ (r_ & 7)) * 8]);
      }
#pragma unroll
      for (int n = 0; n < 4; ++n)
        bfr[n] = *reinterpret_cast<const bf16x8*>(
            &Wt[((size_t)g * N_TOT + colBase + n * 16) * 8]);
      __builtin_amdgcn_s_setprio(1);
#pragma unroll
      for (int m = 0; m < 4; ++m)
#pragma unroll
        for (int n = 0; n < 4; ++n)
          acc[m][n] = __builtin_amdgcn_mfma_f32_16x16x32_bf16(
              af[m], bfr[n], acc[m][n], 0, 0, 0);
      __builtin_amdgcn_s_setprio(0);
    }
  }

  // ---- epilogue: C col = lane&15 (+16n), row = (lane>>4)*4 + j (+16m) ----
  const int row0 = bm * BM + (ksel << 2);
#pragma unroll
  for (int n = 0; n < 4; ++n) {
    const float bv = bias[colBase + n * 16];
#pragma unroll
    for (int m = 0; m < 4; ++m) {
#pragma unroll
      for (int j = 0; j < 4; ++j) {
        __builtin_nontemporal_store(
            acc[m][n][j] + bv,
            &out[(size_t)(row0 + m * 16 + j) * N_TOT + colBase + n * 16]);
      }
    }
  }
}

// ---------------------------------------------------------------------------
extern "C" void kernel_launch(void* const* d_in, const int* in_sizes, int n_in,
                              void* d_out, int out_size, void* d_ws,
                              size_t ws_size, hipStream_t stream) {
  const int*   words = (const int*)d_in[0];
  const float* E     = (const float*)d_in[1];
  const float* W     = (const float*)d_in[2];
  const float* b     = (const float*)d_in[3];
  float* out = (float*)d_out;

  ushort* Wtws = (ushort*)d_ws;  // 512*768 bf16, fragment-major

  hipLaunchKernelGGL(wt_kernel, dim3(K_TOT / 64, N_TOT / 64), dim3(256), 0,
                     stream, W, Wtws);
  hipLaunchKernelGGL(fused_kernel, dim3(M_TOT / BM), dim3(512), 0, stream,
                     words, E, Wtws, b, out);
}